// Round 2
// baseline (362.125 us; speedup 1.0000x reference)
//
#include <hip/hip_runtime.h>

// SimpleMovingAverage: history (64, 336, 862, 3) f32.
// window = last 12 timesteps; 336 recursive-mean steps; out (64, 336, 862, 3).
//
// Key identity: the scan is LINEAR in the initial window. out[b,t,sc] =
// sum_k coef[t][k] * in[b, 324+k, sc]. Kernel 1 builds coef[336][12] by
// running the recurrence on the 12 basis vectors (one wave, ~2 us). Kernel 2
// is then embarrassingly parallel (no serial chain): each thread computes
// TT consecutive-t outputs for one sc from 12 register-held inputs.

#define Q 12
#define IN_LEN 336
#define OUT_LEN 336
#define NB 64
#define SC (862 * 3)   // 2586: contiguous (series, channel) extent per (b, t)
#define TT 12          // timesteps per thread in the main kernel (336 = 28*12)

// ---- Kernel 1: coefficient table via basis-vector recurrence ----
__global__ __launch_bounds__(64) void
sma_coef_kernel(float* __restrict__ coef /* [OUT_LEN][Q] */) {
    const int k = threadIdx.x;          // basis index
    if (k >= Q) return;

    float w[Q];
#pragma unroll
    for (int j = 0; j < Q; ++j) w[j] = (j == k) ? 1.0f : 0.0f;
    float sum = 1.0f;
    const float inv = 1.0f / (float)Q;

    for (int t = 0; t < OUT_LEN; t += Q) {
#pragma unroll
        for (int j = 0; j < Q; ++j) {
            const float m = sum * inv;
            sum += m - w[j];
            w[j] = m;
            coef[(t + j) * Q + k] = m;
        }
        // re-anchor running sum to kill FP drift
        float s = 0.f;
#pragma unroll
        for (int j = 0; j < Q; ++j) s += w[j];
        sum = s;
    }
}

// ---- Kernel 2: fully parallel apply ----
__global__ __launch_bounds__(256) void
sma_apply_kernel(const float* __restrict__ in,
                 const float* __restrict__ coef,
                 float* __restrict__ out) {
    const int sc = blockIdx.x * blockDim.x + threadIdx.x;
    if (sc >= SC) return;
    const int b  = blockIdx.z;
    const int t0 = blockIdx.y * TT;

    // Load this series' 12 initial-window values (coalesced per k).
    const float* inp = in + ((size_t)(b * IN_LEN + (IN_LEN - Q)) * SC + sc);
    float x[Q];
#pragma unroll
    for (int k = 0; k < Q; ++k) x[k] = inp[(size_t)k * SC];

    float* op = out + ((size_t)(b * OUT_LEN + t0) * SC + sc);
#pragma unroll
    for (int j = 0; j < TT; ++j) {
        // coef row is wave-uniform (depends only on blockIdx.y) -> scalar loads
        const float* c = coef + (size_t)(t0 + j) * Q;
        float acc = 0.f;
#pragma unroll
        for (int k = 0; k < Q; ++k) acc = fmaf(c[k], x[k], acc);
        op[(size_t)j * SC] = acc;   // wave writes 256B contiguous
    }
}

extern "C" void kernel_launch(void* const* d_in, const int* in_sizes, int n_in,
                              void* d_out, int out_size, void* d_ws, size_t ws_size,
                              hipStream_t stream) {
    const float* in = (const float*)d_in[0];
    float* out  = (float*)d_out;
    float* coef = (float*)d_ws;      // needs OUT_LEN*Q*4 = 16128 bytes

    sma_coef_kernel<<<1, 64, 0, stream>>>(coef);

    const int block = 256;
    dim3 grid((SC + block - 1) / block,   // 11
              OUT_LEN / TT,               // 28
              NB);                        // 64  -> 19,712 blocks
    sma_apply_kernel<<<grid, block, 0, stream>>>(in, coef, out);
}

// Round 3
// 340.982 us; speedup vs baseline: 1.0620x; 1.0620x over previous
//
#include <hip/hip_runtime.h>

// SimpleMovingAverage: history (64, 336, 862, 3) f32 -> out (64, 336, 862, 3).
// The scan is LINEAR in the last-12 window: out[b,t,sc] = sum_k coef[t][k]*x[b,k,sc].
// coef is input-independent -> computed at COMPILE TIME into __constant__ memory.
// Single fully-parallel kernel, float2-vectorized (SC = 2586 = 2*1293, rows 8B-aligned).

#define Q 12
#define IN_LEN 336
#define OUT_LEN 336
#define NB 64
#define SC2 1293        // SC/2 in float2 units (862*3/2)
#define TT 12           // t-values per thread (336 = 28*12)

struct Coefs { float c[OUT_LEN][Q]; };

// Compile-time evaluation of the recurrence on the 12 basis vectors.
constexpr Coefs make_coefs() {
    Coefs tbl{};
    for (int k = 0; k < Q; ++k) {
        float w[Q] = {};
        w[k] = 1.0f;
        float sum = 1.0f;
        for (int step = 0; step < OUT_LEN; ++step) {
            const int j = step % Q;
            const float m = sum * (1.0f / 12.0f);
            sum += m - w[j];         // drop oldest, append mean
            w[j] = m;
            tbl.c[step][k] = m;
            if (j == Q - 1) {        // re-anchor running sum: kill FP drift
                float s = 0.0f;
                for (int i = 0; i < Q; ++i) s += w[i];
                sum = s;
            }
        }
    }
    return tbl;
}

__constant__ Coefs g_coef = make_coefs();

__global__ __launch_bounds__(256) void
SimpleMovingAverage_22144851378808_kernel(const float2* __restrict__ in,
                                          float2* __restrict__ out) {
    const int g = blockIdx.x * 256 + threadIdx.x;
    if (g >= NB * SC2) return;
    const int b  = g / SC2;               // one magic-mul divide
    const int sc = g - b * SC2;
    const int t0 = blockIdx.y * TT;       // wave-uniform

    // 12 initial-window float2 loads (coalesced per k; L2/L3-resident re-reads).
    const float2* ip = in + ((size_t)(b * IN_LEN + (IN_LEN - Q)) * SC2 + sc);
    float2 x[Q];
#pragma unroll
    for (int k = 0; k < Q; ++k) x[k] = ip[(size_t)k * SC2];

    float2* op = out + ((size_t)(b * OUT_LEN + t0) * SC2 + sc);
#pragma unroll
    for (int j = 0; j < TT; ++j) {
        float ax = 0.0f, ay = 0.0f;
#pragma unroll
        for (int k = 0; k < Q; ++k) {
            const float ck = g_coef.c[t0 + j][k];   // uniform -> scalar load
            ax = fmaf(ck, x[k].x, ax);
            ay = fmaf(ck, x[k].y, ay);
        }
        op[(size_t)j * SC2] = make_float2(ax, ay);  // 512B/wave contiguous
    }
}

extern "C" void kernel_launch(void* const* d_in, const int* in_sizes, int n_in,
                              void* d_out, int out_size, void* d_ws, size_t ws_size,
                              hipStream_t stream) {
    const float2* in = (const float2*)d_in[0];
    float2* out = (float2*)d_out;
    dim3 grid((NB * SC2 + 255) / 256,   // 324
              OUT_LEN / TT,             // 28   -> 9072 blocks
              1);
    SimpleMovingAverage_22144851378808_kernel<<<grid, 256, 0, stream>>>(in, out);
}